// Round 6
// baseline (18674.890 us; speedup 1.0000x reference)
//
#include <hip/hip_runtime.h>
#include <hip/hip_bf16.h>

// 2-layer GRU encoder, T=4096, H=1024.
// v6 = v5 + three fixes:
//  (a) weights FORCED register-resident: no __restrict on weight ptrs,
//      opaque-pointer asm + value pins; __launch_bounds__(512,2) caps 256 VGPR.
//  (b) conflict-free y0 LDS staging (transposed: lane l <-> word k*64+l).
//  (c) s_sleep backoff in poll loops (L3 contention relief).

#define TT    4096
#define HDIM  1024
#define L0WG  64
#define L1WG  128
#define SBS   512
#define FSTR  16          // flag stride in words (64B)

#define PIN4(v) asm volatile("" : "+v"(v.x), "+v"(v.y), "+v"(v.z), "+v"(v.w))

// ---------------- embedding gather ----------------
__global__ void embed_kernel(const int* __restrict__ idx,
                             const float* __restrict__ emb,
                             float* __restrict__ x) {
    int t = blockIdx.x;
    int row = idx[t];
    const float4* src = reinterpret_cast<const float4*>(emb + (size_t)row * HDIM);
    float4* dst = reinterpret_cast<float4*>(x + (size_t)t * HDIM);
    dst[threadIdx.x] = src[threadIdx.x];
}

// ---------------- fp32 NT GEMM: C[M,N] = A[M,K] * B[N,K]^T + bias[N] ----------------
#define BM 64
#define BN 64
#define BK 32
__global__ __launch_bounds__(256)
void gemm_nt_bias(const float* __restrict__ A,
                  const float* __restrict__ Bw,
                  const float* __restrict__ bias,
                  float* __restrict__ C,
                  int M, int N, int K) {
    __shared__ float As[BK][BM];
    __shared__ float Bs[BK][BN];
    const int tid = threadIdx.x;
    const int m0 = blockIdx.x * BM;
    const int n0 = blockIdx.y * BN;
    const int tx = tid & 15, ty = tid >> 4;
    const int lr = tid >> 3;
    const int lc = (tid & 7) * 4;

    float acc[4][4] = {};

    for (int k0 = 0; k0 < K; k0 += BK) {
#pragma unroll
        for (int pass = 0; pass < 2; ++pass) {
            int m = lr + pass * 32;
            float4 v = *reinterpret_cast<const float4*>(A + (size_t)(m0 + m) * K + k0 + lc);
            As[lc + 0][m] = v.x; As[lc + 1][m] = v.y;
            As[lc + 2][m] = v.z; As[lc + 3][m] = v.w;
            float4 u = *reinterpret_cast<const float4*>(Bw + (size_t)(n0 + m) * K + k0 + lc);
            Bs[lc + 0][m] = u.x; Bs[lc + 1][m] = u.y;
            Bs[lc + 2][m] = u.z; Bs[lc + 3][m] = u.w;
        }
        __syncthreads();
#pragma unroll
        for (int kk = 0; kk < BK; ++kk) {
            float4 a = *reinterpret_cast<const float4*>(&As[kk][ty * 4]);
            float4 b = *reinterpret_cast<const float4*>(&Bs[kk][tx * 4]);
            float av[4] = {a.x, a.y, a.z, a.w};
            float bv[4] = {b.x, b.y, b.z, b.w};
#pragma unroll
            for (int i = 0; i < 4; ++i)
#pragma unroll
                for (int j = 0; j < 4; ++j)
                    acc[i][j] = fmaf(av[i], bv[j], acc[i][j]);
        }
        __syncthreads();
    }

    float4 b4 = *reinterpret_cast<const float4*>(bias + n0 + tx * 4);
    float bb[4] = {b4.x, b4.y, b4.z, b4.w};
#pragma unroll
    for (int i = 0; i < 4; ++i) {
        int m = m0 + ty * 4 + i;
        float4 o;
        o.x = acc[i][0] + bb[0];
        o.y = acc[i][1] + bb[1];
        o.z = acc[i][2] + bb[2];
        o.w = acc[i][3] + bb[3];
        *reinterpret_cast<float4*>(C + (size_t)m * N + n0 + tx * 4) = o;
    }
}

// ---------------- fused pipelined scan v6 ----------------
__device__ __forceinline__ float dot4(float4 a, float4 b) {
    return fmaf(a.x, b.x, fmaf(a.y, b.y, fmaf(a.z, b.z, a.w * b.w)));
}
__device__ __forceinline__ float fsig(float x) {
    return 1.f / (1.f + __expf(-x));
}
__device__ __forceinline__ float ftanh(float x) {
    return fmaf(-2.f, 1.f / (1.f + __expf(2.f * x)), 1.f);
}
__device__ __forceinline__ unsigned long long pack_h(unsigned seq, float h) {
    return ((unsigned long long)seq << 32) | (unsigned long long)__float_as_uint(h);
}
__device__ __forceinline__ unsigned long long poll_h(const unsigned long long* p,
                                                     unsigned need) {
    unsigned long long v = __hip_atomic_load(p, __ATOMIC_RELAXED, __HIP_MEMORY_SCOPE_AGENT);
    while ((unsigned)(v >> 32) < need) {
        __builtin_amdgcn_s_sleep(1);
        v = __hip_atomic_load(p, __ATOMIC_RELAXED, __HIP_MEMORY_SCOPE_AGENT);
    }
    return v;
}

__global__ __launch_bounds__(SBS, 2)
void gru_pipe(const float* __restrict__ gi0,   // [T,3H]
              const float* whh0,               // [3H,H]  (no restrict: block remat)
              const float* __restrict__ bhh0,  // [3H]
              const float* wih1,               // [3H,H]
              const float* whh1,               // [3H,H]
              const float* __restrict__ bih1,  // [3H]
              const float* __restrict__ bhh1,  // [3H]
              float* ys0,                      // [T,H] agent-coherent
              float* __restrict__ out,         // [T*H + 2H]
              unsigned long long* h0t,         // [2][H] tagged
              unsigned long long* h1t,         // [2][H] tagged
              unsigned* flags0) {              // [2][L0WG*FSTR]
    const int tid  = threadIdx.x;
    const int slot = tid >> 3;   // 0..63
    const int l8   = tid & 7;

    __shared__ float lds_h[HDIM];
    __shared__ float lds_y[HDIM];
    __shared__ float lds_gh[48];

    if (blockIdx.x < L0WG) {
        // ================= layer 0 =================
        const int g = blockIdx.x;

        const float* wp = whh0;
        asm volatile("" : "+s"(wp));    // opaque: loads can't be re-derived

        float4 Wlo[16], Whi[16];
        if (slot < 48) {
            const int q = slot >> 4, jl = slot & 15;
            const float4* row4 = reinterpret_cast<const float4*>(
                wp + (size_t)(q * HDIM + g * 16 + jl) * HDIM);
#pragma unroll
            for (int k4 = 0; k4 < 16; ++k4) Wlo[k4] = row4[k4 * 8 + l8];
#pragma unroll
            for (int k4 = 0; k4 < 16; ++k4) Whi[k4] = row4[(k4 + 16) * 8 + l8];
        } else {
#pragma unroll
            for (int k4 = 0; k4 < 16; ++k4) { Wlo[k4] = float4{0,0,0,0}; Whi[k4] = float4{0,0,0,0}; }
        }
#pragma unroll
        for (int k4 = 0; k4 < 16; ++k4) { PIN4(Wlo[k4]); PIN4(Whi[k4]); }

        float bh0 = 0.f, bh1 = 0.f, bh2 = 0.f;
        float gir = 0.f, giz = 0.f, gin = 0.f;
        float h_own = 0.f;
        if (tid < 16) {
            const int gj = g * 16 + tid;
            bh0 = bhh0[0 * HDIM + gj];
            bh1 = bhh0[1 * HDIM + gj];
            bh2 = bhh0[2 * HDIM + gj];
            gir = gi0[gj];
            giz = gi0[HDIM + gj];
            gin = gi0[2 * HDIM + gj];
        }

        lds_h[tid] = 0.f;
        lds_h[tid + SBS] = 0.f;
        __syncthreads();

        const float4* lh4 = reinterpret_cast<const float4*>(lds_h);

        for (int t = 0; t < TT; ++t) {
            // prefetch gi0[t+1]
            float nir = 0.f, niz = 0.f, nin = 0.f;
            if (tid < 16 && t + 1 < TT) {
                const float* base = gi0 + (size_t)(t + 1) * 3 * HDIM + g * 16 + tid;
                nir = base[0];
                niz = base[HDIM];
                nin = base[2 * HDIM];
            }

            // phase A
            if (slot < 48) {
                float p0 = 0.f, p1 = 0.f;
#pragma unroll
                for (int k4 = 0; k4 < 16; ++k4) p0 += dot4(Wlo[k4], lh4[k4 * 8 + l8]);
#pragma unroll
                for (int k4 = 0; k4 < 16; ++k4) p1 += dot4(Whi[k4], lh4[(k4 + 16) * 8 + l8]);
                float p = p0 + p1;
                p += __shfl_xor(p, 1);
                p += __shfl_xor(p, 2);
                p += __shfl_xor(p, 4);
                if (l8 == 0) lds_gh[slot] = p;
            }
            __syncthreads();   // S1

            // phase B (wave0 lanes 0..15): gates; publish tagged h
            if (tid < 16) {
                const int gj = g * 16 + tid;
                const float hr = lds_gh[tid]      + bh0;
                const float hz = lds_gh[16 + tid] + bh1;
                const float hn = lds_gh[32 + tid] + bh2;
                const float r = fsig(gir + hr);
                const float z = fsig(giz + hz);
                const float n = ftanh(gin + r * hn);
                const float h_new = (1.f - z) * n + z * h_own;
                h_own = h_new;
                __hip_atomic_store(h0t + ((t + 1) & 1) * HDIM + gj,
                                   pack_h((unsigned)(t + 1), h_new),
                                   __ATOMIC_RELAXED, __HIP_MEMORY_SCOPE_AGENT);
                __hip_atomic_store(ys0 + (size_t)t * HDIM + gj, h_new,
                                   __ATOMIC_RELAXED, __HIP_MEMORY_SCOPE_AGENT);
                if (t == TT - 1) out[(size_t)TT * HDIM + gj] = h_new;
            }
            // y0-readiness flag for layer 1 (off h critical path)
            if (tid == 0) {
                __threadfence();
                __hip_atomic_store(flags0 + (t & 1) * (L0WG * FSTR) + g * FSTR,
                                   (unsigned)(t + 1),
                                   __ATOMIC_RELAXED, __HIP_MEMORY_SCOPE_AGENT);
            }

            // poll own 2 h units (data-in-tag: poll == load)
            {
                const unsigned need = (unsigned)(t + 1);
                const unsigned long long* hp = h0t + ((t + 1) & 1) * HDIM;
                unsigned long long v0 = poll_h(hp + 2 * tid, need);
                unsigned long long v1 = poll_h(hp + 2 * tid + 1, need);
                float2 hv;
                hv.x = __uint_as_float((unsigned)v0);
                hv.y = __uint_as_float((unsigned)v1);
                reinterpret_cast<float2*>(lds_h)[tid] = hv;
            }
            gir = nir; giz = niz; gin = nin;
            __syncthreads();   // S2
        }
    } else {
        // ================= layer 1 =================
        const int g1 = blockIdx.x - L0WG;   // 0..127, units u = g1*8..+8

        const float* wpA = whh1;
        const float* wpB = wih1;
        asm volatile("" : "+s"(wpA), "+s"(wpB));

        // slots 0..23: whh1 rows; slots 24..47: wih1 rows (8 units each)
        float4 Wlo[16], Whi[16];
        if (slot < 48) {
            const int ss = (slot < 24) ? slot : slot - 24;
            const int q = ss >> 3, jl = ss & 7;
            const float* mat = (slot < 24) ? wpA : wpB;
            const float4* row4 = reinterpret_cast<const float4*>(
                mat + (size_t)(q * HDIM + g1 * 8 + jl) * HDIM);
#pragma unroll
            for (int k4 = 0; k4 < 16; ++k4) Wlo[k4] = row4[k4 * 8 + l8];
#pragma unroll
            for (int k4 = 0; k4 < 16; ++k4) Whi[k4] = row4[(k4 + 16) * 8 + l8];
        } else {
#pragma unroll
            for (int k4 = 0; k4 < 16; ++k4) { Wlo[k4] = float4{0,0,0,0}; Whi[k4] = float4{0,0,0,0}; }
        }
#pragma unroll
        for (int k4 = 0; k4 < 16; ++k4) { PIN4(Wlo[k4]); PIN4(Whi[k4]); }

        float bh0 = 0.f, bh1 = 0.f, bh2 = 0.f;
        float bi0 = 0.f, bi1 = 0.f, bi2 = 0.f;
        float h_own = 0.f;
        if (tid < 8) {
            const int u = g1 * 8 + tid;
            bh0 = bhh1[0 * HDIM + u];
            bh1 = bhh1[1 * HDIM + u];
            bh2 = bhh1[2 * HDIM + u];
            bi0 = bih1[0 * HDIM + u];
            bi1 = bih1[1 * HDIM + u];
            bi2 = bih1[2 * HDIM + u];
        }

        lds_h[tid] = 0.f;
        lds_h[tid + SBS] = 0.f;
        // stage y0[0]: wave 7 waits flags0 then pulls (transposed, conflict-free)
        if (tid >= 448) {
            const int l = tid - 448;
            const unsigned* f = flags0 + 0 * (L0WG * FSTR) + l * FSTR;
            while (__hip_atomic_load(f, __ATOMIC_RELAXED, __HIP_MEMORY_SCOPE_AGENT) < 1u)
                __builtin_amdgcn_s_sleep(2);
            const unsigned long long* ysrc = reinterpret_cast<const unsigned long long*>(ys0);
#pragma unroll
            for (int k = 0; k < 8; ++k) {
                unsigned long long yv = __hip_atomic_load(ysrc + k * 64 + l, __ATOMIC_RELAXED,
                                                          __HIP_MEMORY_SCOPE_AGENT);
                float2 yf;
                yf.x = __uint_as_float((unsigned)yv);
                yf.y = __uint_as_float((unsigned)(yv >> 32));
                reinterpret_cast<float2*>(lds_y)[k * 64 + l] = yf;
            }
        }
        __syncthreads();

        const float4* lh4 = reinterpret_cast<const float4*>(lds_h);
        const float4* ly4 = reinterpret_cast<const float4*>(lds_y);

        for (int t = 0; t < TT; ++t) {
            // phase A: 24 whh rows on lds_h + 24 wih rows on lds_y
            if (slot < 48) {
                const float4* s4 = (slot < 24) ? lh4 : ly4;
                float p0 = 0.f, p1 = 0.f;
#pragma unroll
                for (int k4 = 0; k4 < 16; ++k4) p0 += dot4(Wlo[k4], s4[k4 * 8 + l8]);
#pragma unroll
                for (int k4 = 0; k4 < 16; ++k4) p1 += dot4(Whi[k4], s4[(k4 + 16) * 8 + l8]);
                float p = p0 + p1;
                p += __shfl_xor(p, 1);
                p += __shfl_xor(p, 2);
                p += __shfl_xor(p, 4);
                if (l8 == 0) lds_gh[slot] = p;
            }
            __syncthreads();   // S1

            // phase B (lanes 0..7): gates; publish tagged h1
            if (tid < 8) {
                const int u = g1 * 8 + tid;
                const float hr = lds_gh[tid]      + bh0;
                const float hz = lds_gh[8 + tid]  + bh1;
                const float hn = lds_gh[16 + tid] + bh2;
                const float ir = lds_gh[24 + tid] + bi0;
                const float iz = lds_gh[32 + tid] + bi1;
                const float in_ = lds_gh[40 + tid] + bi2;
                const float r = fsig(ir + hr);
                const float z = fsig(iz + hz);
                const float n = ftanh(in_ + r * hn);
                const float h_new = (1.f - z) * n + z * h_own;
                h_own = h_new;
                __hip_atomic_store(h1t + ((t + 1) & 1) * HDIM + u,
                                   pack_h((unsigned)(t + 1), h_new),
                                   __ATOMIC_RELAXED, __HIP_MEMORY_SCOPE_AGENT);
                out[(size_t)t * HDIM + u] = h_new;
                if (t == TT - 1) out[(size_t)TT * HDIM + HDIM + u] = h_new;
            }

            // wave 7: stage y0[t+1] (flag poll + transposed pull)
            if (tid >= 448 && t + 1 < TT) {
                const int l = tid - 448;
                const unsigned* f = flags0 + ((t + 1) & 1) * (L0WG * FSTR) + l * FSTR;
                while (__hip_atomic_load(f, __ATOMIC_RELAXED, __HIP_MEMORY_SCOPE_AGENT)
                       < (unsigned)(t + 2))
                    __builtin_amdgcn_s_sleep(1);
                const unsigned long long* ysrc =
                    reinterpret_cast<const unsigned long long*>(ys0 + (size_t)(t + 1) * HDIM);
#pragma unroll
                for (int k = 0; k < 8; ++k) {
                    unsigned long long yv = __hip_atomic_load(ysrc + k * 64 + l, __ATOMIC_RELAXED,
                                                              __HIP_MEMORY_SCOPE_AGENT);
                    float2 yf;
                    yf.x = __uint_as_float((unsigned)yv);
                    yf.y = __uint_as_float((unsigned)(yv >> 32));
                    reinterpret_cast<float2*>(lds_y)[k * 64 + l] = yf;
                }
            }

            // all threads: poll own 2 h1 units
            {
                const unsigned need = (unsigned)(t + 1);
                const unsigned long long* hp = h1t + ((t + 1) & 1) * HDIM;
                unsigned long long v0 = poll_h(hp + 2 * tid, need);
                unsigned long long v1 = poll_h(hp + 2 * tid + 1, need);
                float2 hv;
                hv.x = __uint_as_float((unsigned)v0);
                hv.y = __uint_as_float((unsigned)v1);
                reinterpret_cast<float2*>(lds_h)[tid] = hv;
            }
            __syncthreads();   // S2
        }
    }
}

// ---------------- launch ----------------
extern "C" void kernel_launch(void* const* d_in, const int* in_sizes, int n_in,
                              void* d_out, int out_size, void* d_ws, size_t ws_size,
                              hipStream_t stream) {
    const int*   idx = (const int*)d_in[0];
    const float* emb = (const float*)d_in[1];
    const float* wih = (const float*)d_in[2];
    const float* whh = (const float*)d_in[3];
    const float* bih = (const float*)d_in[4];
    const float* bhh = (const float*)d_in[5];
    float* out = (float*)d_out;

    float* x    = (float*)d_ws;                 // [T,H]
    float* gi   = x   + (size_t)TT * HDIM;      // [T,3H]
    float* ys0  = gi  + (size_t)TT * 3 * HDIM;  // [T,H]
    float* ctrl = ys0 + (size_t)TT * HDIM;
    unsigned long long* h0t = (unsigned long long*)ctrl;   // [2][H]
    unsigned long long* h1t = h0t + 2 * HDIM;              // [2][H]
    unsigned* flags0 = (unsigned*)(h1t + 2 * HDIM);        // [2][L0WG*FSTR]
    size_t ctrl_bytes = (size_t)(4 * HDIM) * 8 + (size_t)(2 * L0WG * FSTR) * 4;

    hipMemsetAsync(ctrl, 0, ctrl_bytes, stream);

    embed_kernel<<<TT, 256, 0, stream>>>(idx, emb, x);

    const size_t wstride = (size_t)3 * HDIM * HDIM;
    const size_t bstride = (size_t)3 * HDIM;

    gemm_nt_bias<<<dim3(TT / BM, 3 * HDIM / BN), 256, 0, stream>>>(
        x, wih, bih, gi, TT, 3 * HDIM, HDIM);

    gru_pipe<<<L0WG + L1WG, SBS, 0, stream>>>(
        gi, whh, bhh,
        wih + wstride, whh + wstride, bih + bstride, bhh + bstride,
        ys0, out, h0t, h1t, flags0);
}